// Round 12
// baseline (1590.304 us; speedup 1.0000x reference)
//
#include <hip/hip_runtime.h>

#define NN 50000     // nodes
#define NE 800000    // edges
#define DD 64        // channels
#define NG 512       // graphs
#define NL 5         // layers
#define NSLICE 8
#define SLICEW 6250  // NN / NSLICE
#define SCAP 131072  // staging capacity per slice (expect ~100k, +105 sigma)

// ---------------- CSR build (by dst) ----------------

__global__ void count_deg_k(const int* __restrict__ dst, int* __restrict__ deg) {
    int e = blockIdx.x * blockDim.x + threadIdx.x;
    if (e < NE) atomicAdd(&deg[dst[e]], 1);
}

// start[i] = exclusive prefix of deg, allocated via one atomic per wave
__global__ void calc_start_k(const int* __restrict__ deg, int* __restrict__ start,
                             int* __restrict__ cursor) {
    int i = blockIdx.x * blockDim.x + threadIdx.x;
    int lane = threadIdx.x & 63;
    int d = (i < NN) ? deg[i] : 0;
    int incl = d;
#pragma unroll
    for (int off = 1; off < 64; off <<= 1) {
        int t = __shfl_up(incl, off, 64);
        if (lane >= off) incl += t;
    }
    int total = __shfl(incl, 63, 64);
    int base = 0;
    if (lane == 0 && total > 0) base = atomicAdd(cursor, total);
    base = __shfl(base, 0, 64);
    if (i < NN) start[i] = base + incl - d;
}

// Phase A: bin edges into 8 dst-slices. Wave-level ballot allocation ->
// each wave appends contiguous runs (~full cache lines) to its slice lists.
// NE == 3125 * 256 exactly: no tail, every lane active.
__global__ void bin_k(const int* __restrict__ src, const int* __restrict__ dst,
                      int* __restrict__ scur, uint2* __restrict__ staging) {
    int e = blockIdx.x * 256 + threadIdx.x;
    int lane = threadIdx.x & 63;
    int d = dst[e];
    int sv = src[e];
    int s = d / SLICEW;                    // 0..7
    unsigned long long lanebit = 1ull << lane;
#pragma unroll
    for (int b = 0; b < NSLICE; ++b) {
        unsigned long long mask = __ballot(s == b);
        if (s == b) {
            int leader = (int)__ffsll((long long)mask) - 1;
            int cnt = (int)__popcll(mask);
            int base = 0;
            if (lane == leader) base = atomicAdd(&scur[b], cnt);
            base = __shfl(base, leader, 64);
            int off = (int)__popcll(mask & (lanebit - 1));
            staging[(size_t)b * SCAP + base + off] = make_uint2((unsigned)sv, (unsigned)d);
        }
    }
}

// Phase B: XCD-affine scatter. slice = blockIdx&7; each group's col window
// (~400 KB) + fcnt window (25 KB) stay hot in one XCD's L2.
__global__ void scatter_k(const int* __restrict__ scur, const uint2* __restrict__ staging,
                          const int* __restrict__ start, int* __restrict__ fcnt,
                          int* __restrict__ col) {
    int s = blockIdx.x & (NSLICE - 1);
    int bi = blockIdx.x >> 3;
    int stride = (gridDim.x >> 3) * blockDim.x;
    int n = scur[s];
    const uint2* st = staging + (size_t)s * SCAP;
    for (int i = bi * blockDim.x + threadIdx.x; i < n; i += stride) {
        uint2 u = st[i];
        int d = (int)u.y;
        int p = atomicAdd(&fcnt[d], 1);
        col[start[d] + p] = (int)u.x;
    }
}

// ---------------- aggregation v5 (R10-proven best) ----------------
// one wave per node; lanes = 4 edge-groups x 16 channel-quads.
// Per 32-edge chunk: ONE col load (lanes 0..31), nb via __shfl; 4 gathers
// unconditional + 4 under wave-uniform cnt>16 -> up to 8 loads in flight.
__global__ void aggregate_k(const float* __restrict__ h, const int* __restrict__ start,
                            const int* __restrict__ deg, const int* __restrict__ col,
                            float* __restrict__ agg) {
    int w = (blockIdx.x * blockDim.x + threadIdx.x) >> 6;
    int lane = threadIdx.x & 63;
    if (w >= NN) return;
    int eg = lane >> 4;   // edge group 0..3
    int cl = lane & 15;   // channel quad
    int s = start[w], d = deg[w];
    float4 acc0 = make_float4(0.f, 0.f, 0.f, 0.f);
    float4 acc1 = make_float4(0.f, 0.f, 0.f, 0.f);
    const float4* h4 = (const float4*)h;
    for (int base = 0; base < d; base += 32) {
        int idx = base + (lane & 31);
        int cv = col[s + ((idx < d) ? idx : 0)];
        int cnt = d - base;
        float4 v0, v1, v2, v3;
        {
            int n0 = __shfl(cv, eg +  0, 64);
            int n1 = __shfl(cv, eg +  4, 64);
            int n2 = __shfl(cv, eg +  8, 64);
            int n3 = __shfl(cv, eg + 12, 64);
            v0 = h4[(size_t)n0 * 16 + cl];
            v1 = h4[(size_t)n1 * 16 + cl];
            v2 = h4[(size_t)n2 * 16 + cl];
            v3 = h4[(size_t)n3 * 16 + cl];
        }
        float4 v4, v5, v6, v7;
        bool hi = (cnt > 16);
        if (hi) {
            int n4 = __shfl(cv, eg + 16, 64);
            int n5 = __shfl(cv, eg + 20, 64);
            int n6 = __shfl(cv, eg + 24, 64);
            int n7 = __shfl(cv, eg + 28, 64);
            v4 = h4[(size_t)n4 * 16 + cl];
            v5 = h4[(size_t)n5 * 16 + cl];
            v6 = h4[(size_t)n6 * 16 + cl];
            v7 = h4[(size_t)n7 * 16 + cl];
        }
        if (eg + 0 < cnt)  { acc0.x += v0.x; acc0.y += v0.y; acc0.z += v0.z; acc0.w += v0.w; }
        if (eg + 4 < cnt)  { acc1.x += v1.x; acc1.y += v1.y; acc1.z += v1.z; acc1.w += v1.w; }
        if (eg + 8 < cnt)  { acc0.x += v2.x; acc0.y += v2.y; acc0.z += v2.z; acc0.w += v2.w; }
        if (eg + 12 < cnt) { acc1.x += v3.x; acc1.y += v3.y; acc1.z += v3.z; acc1.w += v3.w; }
        if (hi) {
            if (eg + 16 < cnt) { acc0.x += v4.x; acc0.y += v4.y; acc0.z += v4.z; acc0.w += v4.w; }
            if (eg + 20 < cnt) { acc1.x += v5.x; acc1.y += v5.y; acc1.z += v5.z; acc1.w += v5.w; }
            if (eg + 24 < cnt) { acc0.x += v6.x; acc0.y += v6.y; acc0.z += v6.z; acc0.w += v6.w; }
            if (eg + 28 < cnt) { acc1.x += v7.x; acc1.y += v7.y; acc1.z += v7.z; acc1.w += v7.w; }
        }
    }
    float4 acc;
    acc.x = acc0.x + acc1.x; acc.y = acc0.y + acc1.y;
    acc.z = acc0.z + acc1.z; acc.w = acc0.w + acc1.w;
#pragma unroll
    for (int off = 16; off <= 32; off <<= 1) {
        acc.x += __shfl_xor(acc.x, off, 64);
        acc.y += __shfl_xor(acc.y, off, 64);
        acc.z += __shfl_xor(acc.z, off, 64);
        acc.w += __shfl_xor(acc.w, off, 64);
    }
    if (eg == 0) {
        ((float4*)(agg + (size_t)w * DD))[cl] = acc;
    }
}

// ---------------- dense layer v4 (proven R5/R7/R10) ----------------
template <int RESID>
__global__ void __launch_bounds__(256, 3)
dense_layer_k(const float* __restrict__ agg, const float* __restrict__ hin,
              const float* __restrict__ wrel, const float* __restrict__ brel,
              const float* __restrict__ wroot, float* __restrict__ hout) {
    __shared__ float A[64][68];
    __shared__ float H[64][68];

    const int t = threadIdx.x;
    const int tile = blockIdx.x * 64;
    const int nrows = min(64, NN - tile);

    const float4* agg4 = (const float4*)(agg + (size_t)tile * DD);
    const float4* hin4 = (const float4*)(hin + (size_t)tile * DD);
#pragma unroll
    for (int k = 0; k < 4; ++k) {
        int idx = t + k * 256;
        int row = idx >> 4, cq = idx & 15;
        if (row < nrows) {
            *(float4*)&A[row][4 * cq] = agg4[idx];
            *(float4*)&H[row][4 * cq] = hin4[idx];
        }
    }
    __syncthreads();

    const int lane = t & 63;
    const int wv = __builtin_amdgcn_readfirstlane(t >> 6);
    const int o0 = wv * 16;

    float4 a4[8], h4[8];
    float acc[16];

#pragma unroll
    for (int cq = 0; cq < 8; ++cq) {
        a4[cq] = *(const float4*)&A[lane][4 * cq];
        h4[cq] = *(const float4*)&H[lane][4 * cq];
    }
#pragma unroll
    for (int oo = 0; oo < 16; ++oo) {
        int o = o0 + oo;
        const float* w1 = wrel + o * DD;
        const float* w2 = wroot + o * DD;
        float s0 = 0.f, s1 = 0.f, s2 = 0.f, s3 = 0.f;
#pragma unroll
        for (int cq = 0; cq < 8; ++cq) {
            s0 += a4[cq].x * w1[4 * cq + 0] + h4[cq].x * w2[4 * cq + 0];
            s1 += a4[cq].y * w1[4 * cq + 1] + h4[cq].y * w2[4 * cq + 1];
            s2 += a4[cq].z * w1[4 * cq + 2] + h4[cq].z * w2[4 * cq + 2];
            s3 += a4[cq].w * w1[4 * cq + 3] + h4[cq].w * w2[4 * cq + 3];
        }
        acc[oo] = (s0 + s1) + (s2 + s3);
    }

#pragma unroll
    for (int cq = 0; cq < 8; ++cq) {
        a4[cq] = *(const float4*)&A[lane][32 + 4 * cq];
        h4[cq] = *(const float4*)&H[lane][32 + 4 * cq];
    }
    __syncthreads();
    float* Out = &A[0][0];
#pragma unroll
    for (int oo = 0; oo < 16; ++oo) {
        int o = o0 + oo;
        const float* w1 = wrel + o * DD + 32;
        const float* w2 = wroot + o * DD + 32;
        float s0 = acc[oo], s1 = 0.f, s2 = 0.f, s3 = 0.f;
#pragma unroll
        for (int cq = 0; cq < 8; ++cq) {
            s0 += a4[cq].x * w1[4 * cq + 0] + h4[cq].x * w2[4 * cq + 0];
            s1 += a4[cq].y * w1[4 * cq + 1] + h4[cq].y * w2[4 * cq + 1];
            s2 += a4[cq].z * w1[4 * cq + 2] + h4[cq].z * w2[4 * cq + 2];
            s3 += a4[cq].w * w1[4 * cq + 3] + h4[cq].w * w2[4 * cq + 3];
        }
        Out[lane * 68 + o] = (s0 + s1) + (s2 + s3) + brel[o];
    }
    __syncthreads();

    float4* out4 = (float4*)(hout + (size_t)tile * DD);
#pragma unroll
    for (int k = 0; k < 4; ++k) {
        int idx = t + k * 256;
        int row = idx >> 4, cq = idx & 15;
        if (row < nrows) {
            float4 r = *(const float4*)&A[row][4 * cq];
            if (RESID) {
                float4 hr = *(const float4*)&H[row][4 * cq];
                r.x += hr.x; r.y += hr.y; r.z += hr.z; r.w += hr.w;
            }
            r.x = fmaxf(r.x, 0.f); r.y = fmaxf(r.y, 0.f);
            r.z = fmaxf(r.z, 0.f); r.w = fmaxf(r.w, 0.f);
            out4[idx] = r;
        }
    }
}

// ---------------- pooling (batch is sorted) ----------------

__global__ void pool_k(const float* __restrict__ h, const int* __restrict__ batch,
                       float* __restrict__ sums, int* __restrict__ cnt) {
    const int NP = 32;
    int w = (blockIdx.x * blockDim.x + threadIdx.x) >> 6;
    int lane = threadIdx.x & 63;
    int n0 = w * NP;
    if (n0 >= NN) return;
    int n1 = min(n0 + NP, NN);
    int g = batch[n0];
    float acc = 0.f;
    int run = 0;
    for (int i = n0; i < n1; ++i) {
        int gi = batch[i];
        if (gi != g) {
            atomicAdd(&sums[g * DD + lane], acc);
            if (lane == 0) atomicAdd(&cnt[g], run);
            acc = 0.f; run = 0; g = gi;
        }
        acc += h[i * DD + lane];
        run++;
    }
    atomicAdd(&sums[g * DD + lane], acc);
    if (lane == 0) atomicAdd(&cnt[g], run);
}

// ---------------- head: mean -> linear -> softmax ----------------

__global__ void head_k(const float* __restrict__ sums, const int* __restrict__ cnt,
                       const float* __restrict__ lin_w, const float* __restrict__ lin_b,
                       float* __restrict__ out) {
    int g = blockIdx.x * (blockDim.x >> 6) + (threadIdx.x >> 6);
    int o = threadIdx.x & 63;
    if (g >= NG) return;
    float c = (float)cnt[g];
    float inv = 1.0f / fmaxf(c, 1.0f);
    float acc = lin_b[o];
#pragma unroll 8
    for (int k = 0; k < DD; ++k) {
        acc += sums[g * DD + k] * inv * lin_w[o * DD + k];
    }
    float m = acc;
#pragma unroll
    for (int off = 32; off; off >>= 1) m = fmaxf(m, __shfl_xor(m, off, 64));
    float e = __expf(acc - m);
    float s = e;
#pragma unroll
    for (int off = 32; off; off >>= 1) s += __shfl_xor(s, off, 64);
    out[g * DD + o] = e / s;
}

// ---------------- driver ----------------

extern "C" void kernel_launch(void* const* d_in, const int* in_sizes, int n_in,
                              void* d_out, int out_size, void* d_ws, size_t ws_size,
                              hipStream_t stream) {
    const float* x      = (const float*)d_in[0];
    const int*   edge   = (const int*)d_in[1];   // [2, E]: src = edge, dst = edge+NE
    const int*   batch  = (const int*)d_in[2];
    const float* rel_w  = (const float*)d_in[3]; // [L, D, D]
    const float* rel_b  = (const float*)d_in[4]; // [L, D]
    const float* root_w = (const float*)d_in[5]; // [L, D, D]
    const float* lin_w  = (const float*)d_in[6]; // [D, D]
    const float* lin_b  = (const float*)d_in[7]; // [D]
    float* out = (float*)d_out;

    const int* src = edge;
    const int* dst = edge + NE;

    // workspace carve (all 256B aligned)
    char* p = (char*)d_ws;
    auto carve = [&](size_t bytes) {
        char* r = p;
        p += (bytes + 255) & ~(size_t)255;
        return (void*)r;
    };
    float* hA    = (float*)carve((size_t)NN * DD * 4);
    float* hB    = (float*)carve((size_t)NN * DD * 4);
    float* agg   = (float*)carve((size_t)NN * DD * 4);
    int*   col   = (int*)carve((size_t)NE * 4);
    int*   strt  = (int*)carve((size_t)NN * 4);
    uint2* stage = (uint2*)carve((size_t)NSLICE * SCAP * 8);
    // ---- contiguous zero region (single memset) ----
    char* zbase = p;
    float* sums = (float*)carve((size_t)NG * DD * 4);
    int*   cnt  = (int*)carve((size_t)NG * 4);
    int*   deg  = (int*)carve((size_t)NN * 4);
    int*   fcnt = (int*)carve((size_t)NN * 4);
    int*   scur = (int*)carve((size_t)NSLICE * 4);
    int*   cur  = (int*)carve(4);
    size_t zbytes = (size_t)(p - zbase);

    hipMemsetAsync(zbase, 0, zbytes, stream);

    // CSR build: count -> scan -> bin -> XCD-affine scatter
    count_deg_k<<<(NE + 255) / 256, 256, 0, stream>>>(dst, deg);
    calc_start_k<<<(NN + 255) / 256, 256, 0, stream>>>(deg, strt, cur);
    bin_k<<<NE / 256, 256, 0, stream>>>(src, dst, scur, stage);
    scatter_k<<<8 * 52, 256, 0, stream>>>(scur, stage, strt, fcnt, col);

    const int aggBlocks = (NN + 3) / 4;     // 4 waves (nodes) per block
    const int dnsBlocks = (NN + 63) / 64;   // 64 nodes per block

    // layer 0: x -> hA
    aggregate_k<<<aggBlocks, 256, 0, stream>>>(x, strt, deg, col, agg);
    dense_layer_k<0><<<dnsBlocks, 256, 0, stream>>>(agg, x, rel_w, rel_b, root_w, hA);
    // layer 1: hA -> hB
    aggregate_k<<<aggBlocks, 256, 0, stream>>>(hA, strt, deg, col, agg);
    dense_layer_k<0><<<dnsBlocks, 256, 0, stream>>>(agg, hA, rel_w + 4096, rel_b + 64,
                                                    root_w + 4096, hB);
    // layer 2: hB -> hA
    aggregate_k<<<aggBlocks, 256, 0, stream>>>(hB, strt, deg, col, agg);
    dense_layer_k<0><<<dnsBlocks, 256, 0, stream>>>(agg, hB, rel_w + 2 * 4096, rel_b + 2 * 64,
                                                    root_w + 2 * 4096, hA);
    // layer 3 (residual): hA -> hB
    aggregate_k<<<aggBlocks, 256, 0, stream>>>(hA, strt, deg, col, agg);
    dense_layer_k<1><<<dnsBlocks, 256, 0, stream>>>(agg, hA, rel_w + 3 * 4096, rel_b + 3 * 64,
                                                    root_w + 3 * 4096, hB);
    // layer 4 (residual): hB -> hA
    aggregate_k<<<aggBlocks, 256, 0, stream>>>(hB, strt, deg, col, agg);
    dense_layer_k<1><<<dnsBlocks, 256, 0, stream>>>(agg, hB, rel_w + 4 * 4096, rel_b + 4 * 64,
                                                    root_w + 4 * 4096, hA);

    // pool + head
    const int wavesPool = (NN + 31) / 32;
    pool_k<<<(wavesPool + 3) / 4, 256, 0, stream>>>(hA, batch, sums, cnt);
    head_k<<<(NG + 3) / 4, 256, 0, stream>>>(sums, cnt, lin_w, lin_b, out);
}

// Round 13
// 451.325 us; speedup vs baseline: 3.5236x; 3.5236x over previous
//
#include <hip/hip_runtime.h>

#define NN 50000     // nodes
#define NE 800000    // edges
#define DD 64        // channels
#define NG 512       // graphs
#define NL 5         // layers

// ---------------- CSR build (by dst) ----------------

__global__ void count_deg_k(const int* __restrict__ dst, int* __restrict__ deg) {
    int e = blockIdx.x * blockDim.x + threadIdx.x;
    if (e < NE) atomicAdd(&deg[dst[e]], 1);
}

// start[i] = exclusive prefix of deg, allocated via one atomic per wave
__global__ void calc_start_k(const int* __restrict__ deg, int* __restrict__ start,
                             int* __restrict__ cursor) {
    int i = blockIdx.x * blockDim.x + threadIdx.x;
    int lane = threadIdx.x & 63;
    int d = (i < NN) ? deg[i] : 0;
    int incl = d;
#pragma unroll
    for (int off = 1; off < 64; off <<= 1) {
        int t = __shfl_up(incl, off, 64);
        if (lane >= off) incl += t;
    }
    int total = __shfl(incl, 63, 64);
    int base = 0;
    if (lane == 0 && total > 0) base = atomicAdd(cursor, total);
    base = __shfl(base, 0, 64);
    if (i < NN) start[i] = base + incl - d;
}

// plain scatter (R10-proven; nt-store and binning variants both regressed)
__global__ void fill_col_k(const int* __restrict__ src, const int* __restrict__ dst,
                           const int* __restrict__ start, int* __restrict__ fcnt,
                           int* __restrict__ col) {
    int e = blockIdx.x * blockDim.x + threadIdx.x;
    if (e < NE) {
        int d = dst[e];
        int p = atomicAdd(&fcnt[d], 1);
        col[start[d] + p] = src[e];
    }
}

// ---------------- aggregation v5 (R10-proven best) ----------------
// one wave per node; lanes = 4 edge-groups x 16 channel-quads.
// Per 32-edge chunk: ONE col load (lanes 0..31), nb via __shfl; 4 gathers
// unconditional + 4 under wave-uniform cnt>16 -> up to 8 loads in flight.
__global__ void aggregate_k(const float* __restrict__ h, const int* __restrict__ start,
                            const int* __restrict__ deg, const int* __restrict__ col,
                            float* __restrict__ agg) {
    int w = (blockIdx.x * blockDim.x + threadIdx.x) >> 6;
    int lane = threadIdx.x & 63;
    if (w >= NN) return;
    int eg = lane >> 4;   // edge group 0..3
    int cl = lane & 15;   // channel quad
    int s = start[w], d = deg[w];
    float4 acc0 = make_float4(0.f, 0.f, 0.f, 0.f);
    float4 acc1 = make_float4(0.f, 0.f, 0.f, 0.f);
    const float4* h4 = (const float4*)h;
    for (int base = 0; base < d; base += 32) {
        int idx = base + (lane & 31);
        int cv = col[s + ((idx < d) ? idx : 0)];
        int cnt = d - base;
        float4 v0, v1, v2, v3;
        {
            int n0 = __shfl(cv, eg +  0, 64);
            int n1 = __shfl(cv, eg +  4, 64);
            int n2 = __shfl(cv, eg +  8, 64);
            int n3 = __shfl(cv, eg + 12, 64);
            v0 = h4[(size_t)n0 * 16 + cl];
            v1 = h4[(size_t)n1 * 16 + cl];
            v2 = h4[(size_t)n2 * 16 + cl];
            v3 = h4[(size_t)n3 * 16 + cl];
        }
        float4 v4, v5, v6, v7;
        bool hi = (cnt > 16);
        if (hi) {
            int n4 = __shfl(cv, eg + 16, 64);
            int n5 = __shfl(cv, eg + 20, 64);
            int n6 = __shfl(cv, eg + 24, 64);
            int n7 = __shfl(cv, eg + 28, 64);
            v4 = h4[(size_t)n4 * 16 + cl];
            v5 = h4[(size_t)n5 * 16 + cl];
            v6 = h4[(size_t)n6 * 16 + cl];
            v7 = h4[(size_t)n7 * 16 + cl];
        }
        if (eg + 0 < cnt)  { acc0.x += v0.x; acc0.y += v0.y; acc0.z += v0.z; acc0.w += v0.w; }
        if (eg + 4 < cnt)  { acc1.x += v1.x; acc1.y += v1.y; acc1.z += v1.z; acc1.w += v1.w; }
        if (eg + 8 < cnt)  { acc0.x += v2.x; acc0.y += v2.y; acc0.z += v2.z; acc0.w += v2.w; }
        if (eg + 12 < cnt) { acc1.x += v3.x; acc1.y += v3.y; acc1.z += v3.z; acc1.w += v3.w; }
        if (hi) {
            if (eg + 16 < cnt) { acc0.x += v4.x; acc0.y += v4.y; acc0.z += v4.z; acc0.w += v4.w; }
            if (eg + 20 < cnt) { acc1.x += v5.x; acc1.y += v5.y; acc1.z += v5.z; acc1.w += v5.w; }
            if (eg + 24 < cnt) { acc0.x += v6.x; acc0.y += v6.y; acc0.z += v6.z; acc0.w += v6.w; }
            if (eg + 28 < cnt) { acc1.x += v7.x; acc1.y += v7.y; acc1.z += v7.z; acc1.w += v7.w; }
        }
    }
    float4 acc;
    acc.x = acc0.x + acc1.x; acc.y = acc0.y + acc1.y;
    acc.z = acc0.z + acc1.z; acc.w = acc0.w + acc1.w;
#pragma unroll
    for (int off = 16; off <= 32; off <<= 1) {
        acc.x += __shfl_xor(acc.x, off, 64);
        acc.y += __shfl_xor(acc.y, off, 64);
        acc.z += __shfl_xor(acc.z, off, 64);
        acc.w += __shfl_xor(acc.w, off, 64);
    }
    if (eg == 0) {
        ((float4*)(agg + (size_t)w * DD))[cl] = acc;
    }
}

// ---------------- dense layer v5: 4 blocks/CU ----------------
// Identical to the R10 dense except __launch_bounds__(256,4): register
// demand ~105 VGPR < 128 cap, so no spill, and one extra resident block/CU
// covers the LDS-transpose + barrier phases.
template <int RESID>
__global__ void __launch_bounds__(256, 4)
dense_layer_k(const float* __restrict__ agg, const float* __restrict__ hin,
              const float* __restrict__ wrel, const float* __restrict__ brel,
              const float* __restrict__ wroot, float* __restrict__ hout) {
    __shared__ float A[64][68];
    __shared__ float H[64][68];

    const int t = threadIdx.x;
    const int tile = blockIdx.x * 64;
    const int nrows = min(64, NN - tile);

    const float4* agg4 = (const float4*)(agg + (size_t)tile * DD);
    const float4* hin4 = (const float4*)(hin + (size_t)tile * DD);
#pragma unroll
    for (int k = 0; k < 4; ++k) {
        int idx = t + k * 256;
        int row = idx >> 4, cq = idx & 15;
        if (row < nrows) {
            *(float4*)&A[row][4 * cq] = agg4[idx];
            *(float4*)&H[row][4 * cq] = hin4[idx];
        }
    }
    __syncthreads();

    const int lane = t & 63;
    const int wv = __builtin_amdgcn_readfirstlane(t >> 6);
    const int o0 = wv * 16;

    float4 a4[8], h4[8];
    float acc[16];

#pragma unroll
    for (int cq = 0; cq < 8; ++cq) {
        a4[cq] = *(const float4*)&A[lane][4 * cq];
        h4[cq] = *(const float4*)&H[lane][4 * cq];
    }
#pragma unroll
    for (int oo = 0; oo < 16; ++oo) {
        int o = o0 + oo;
        const float* w1 = wrel + o * DD;
        const float* w2 = wroot + o * DD;
        float s0 = 0.f, s1 = 0.f, s2 = 0.f, s3 = 0.f;
#pragma unroll
        for (int cq = 0; cq < 8; ++cq) {
            s0 += a4[cq].x * w1[4 * cq + 0] + h4[cq].x * w2[4 * cq + 0];
            s1 += a4[cq].y * w1[4 * cq + 1] + h4[cq].y * w2[4 * cq + 1];
            s2 += a4[cq].z * w1[4 * cq + 2] + h4[cq].z * w2[4 * cq + 2];
            s3 += a4[cq].w * w1[4 * cq + 3] + h4[cq].w * w2[4 * cq + 3];
        }
        acc[oo] = (s0 + s1) + (s2 + s3);
    }

#pragma unroll
    for (int cq = 0; cq < 8; ++cq) {
        a4[cq] = *(const float4*)&A[lane][32 + 4 * cq];
        h4[cq] = *(const float4*)&H[lane][32 + 4 * cq];
    }
    __syncthreads();
    float* Out = &A[0][0];
#pragma unroll
    for (int oo = 0; oo < 16; ++oo) {
        int o = o0 + oo;
        const float* w1 = wrel + o * DD + 32;
        const float* w2 = wroot + o * DD + 32;
        float s0 = acc[oo], s1 = 0.f, s2 = 0.f, s3 = 0.f;
#pragma unroll
        for (int cq = 0; cq < 8; ++cq) {
            s0 += a4[cq].x * w1[4 * cq + 0] + h4[cq].x * w2[4 * cq + 0];
            s1 += a4[cq].y * w1[4 * cq + 1] + h4[cq].y * w2[4 * cq + 1];
            s2 += a4[cq].z * w1[4 * cq + 2] + h4[cq].z * w2[4 * cq + 2];
            s3 += a4[cq].w * w1[4 * cq + 3] + h4[cq].w * w2[4 * cq + 3];
        }
        Out[lane * 68 + o] = (s0 + s1) + (s2 + s3) + brel[o];
    }
    __syncthreads();

    float4* out4 = (float4*)(hout + (size_t)tile * DD);
#pragma unroll
    for (int k = 0; k < 4; ++k) {
        int idx = t + k * 256;
        int row = idx >> 4, cq = idx & 15;
        if (row < nrows) {
            float4 r = *(const float4*)&A[row][4 * cq];
            if (RESID) {
                float4 hr = *(const float4*)&H[row][4 * cq];
                r.x += hr.x; r.y += hr.y; r.z += hr.z; r.w += hr.w;
            }
            r.x = fmaxf(r.x, 0.f); r.y = fmaxf(r.y, 0.f);
            r.z = fmaxf(r.z, 0.f); r.w = fmaxf(r.w, 0.f);
            out4[idx] = r;
        }
    }
}

// ---------------- pooling (batch is sorted) ----------------

__global__ void pool_k(const float* __restrict__ h, const int* __restrict__ batch,
                       float* __restrict__ sums, int* __restrict__ cnt) {
    const int NP = 32;
    int w = (blockIdx.x * blockDim.x + threadIdx.x) >> 6;
    int lane = threadIdx.x & 63;
    int n0 = w * NP;
    if (n0 >= NN) return;
    int n1 = min(n0 + NP, NN);
    int g = batch[n0];
    float acc = 0.f;
    int run = 0;
    for (int i = n0; i < n1; ++i) {
        int gi = batch[i];
        if (gi != g) {
            atomicAdd(&sums[g * DD + lane], acc);
            if (lane == 0) atomicAdd(&cnt[g], run);
            acc = 0.f; run = 0; g = gi;
        }
        acc += h[i * DD + lane];
        run++;
    }
    atomicAdd(&sums[g * DD + lane], acc);
    if (lane == 0) atomicAdd(&cnt[g], run);
}

// ---------------- head: mean -> linear -> softmax ----------------

__global__ void head_k(const float* __restrict__ sums, const int* __restrict__ cnt,
                       const float* __restrict__ lin_w, const float* __restrict__ lin_b,
                       float* __restrict__ out) {
    int g = blockIdx.x * (blockDim.x >> 6) + (threadIdx.x >> 6);
    int o = threadIdx.x & 63;
    if (g >= NG) return;
    float c = (float)cnt[g];
    float inv = 1.0f / fmaxf(c, 1.0f);
    float acc = lin_b[o];
#pragma unroll 8
    for (int k = 0; k < DD; ++k) {
        acc += sums[g * DD + k] * inv * lin_w[o * DD + k];
    }
    float m = acc;
#pragma unroll
    for (int off = 32; off; off >>= 1) m = fmaxf(m, __shfl_xor(m, off, 64));
    float e = __expf(acc - m);
    float s = e;
#pragma unroll
    for (int off = 32; off; off >>= 1) s += __shfl_xor(s, off, 64);
    out[g * DD + o] = e / s;
}

// ---------------- driver ----------------

extern "C" void kernel_launch(void* const* d_in, const int* in_sizes, int n_in,
                              void* d_out, int out_size, void* d_ws, size_t ws_size,
                              hipStream_t stream) {
    const float* x      = (const float*)d_in[0];
    const int*   edge   = (const int*)d_in[1];   // [2, E]: src = edge, dst = edge+NE
    const int*   batch  = (const int*)d_in[2];
    const float* rel_w  = (const float*)d_in[3]; // [L, D, D]
    const float* rel_b  = (const float*)d_in[4]; // [L, D]
    const float* root_w = (const float*)d_in[5]; // [L, D, D]
    const float* lin_w  = (const float*)d_in[6]; // [D, D]
    const float* lin_b  = (const float*)d_in[7]; // [D]
    float* out = (float*)d_out;

    const int* src = edge;
    const int* dst = edge + NE;

    // workspace carve (all 256B aligned)
    char* p = (char*)d_ws;
    auto carve = [&](size_t bytes) {
        char* r = p;
        p += (bytes + 255) & ~(size_t)255;
        return (void*)r;
    };
    float* hA   = (float*)carve((size_t)NN * DD * 4);
    float* hB   = (float*)carve((size_t)NN * DD * 4);
    float* agg  = (float*)carve((size_t)NN * DD * 4);
    int*   col  = (int*)carve((size_t)NE * 4);
    int*   strt = (int*)carve((size_t)NN * 4);
    // ---- contiguous zero region (single memset) ----
    char* zbase = p;
    float* sums = (float*)carve((size_t)NG * DD * 4);
    int*   cnt  = (int*)carve((size_t)NG * 4);
    int*   deg  = (int*)carve((size_t)NN * 4);
    int*   fcnt = (int*)carve((size_t)NN * 4);
    int*   cur  = (int*)carve(4);
    size_t zbytes = (size_t)(p - zbase);

    hipMemsetAsync(zbase, 0, zbytes, stream);

    // CSR build
    count_deg_k<<<(NE + 255) / 256, 256, 0, stream>>>(dst, deg);
    calc_start_k<<<(NN + 255) / 256, 256, 0, stream>>>(deg, strt, cur);
    fill_col_k<<<(NE + 255) / 256, 256, 0, stream>>>(src, dst, strt, fcnt, col);

    const int aggBlocks = (NN + 3) / 4;     // 4 waves (nodes) per block
    const int dnsBlocks = (NN + 63) / 64;   // 64 nodes per block

    // layer 0: x -> hA
    aggregate_k<<<aggBlocks, 256, 0, stream>>>(x, strt, deg, col, agg);
    dense_layer_k<0><<<dnsBlocks, 256, 0, stream>>>(agg, x, rel_w, rel_b, root_w, hA);
    // layer 1: hA -> hB
    aggregate_k<<<aggBlocks, 256, 0, stream>>>(hA, strt, deg, col, agg);
    dense_layer_k<0><<<dnsBlocks, 256, 0, stream>>>(agg, hA, rel_w + 4096, rel_b + 64,
                                                    root_w + 4096, hB);
    // layer 2: hB -> hA
    aggregate_k<<<aggBlocks, 256, 0, stream>>>(hB, strt, deg, col, agg);
    dense_layer_k<0><<<dnsBlocks, 256, 0, stream>>>(agg, hB, rel_w + 2 * 4096, rel_b + 2 * 64,
                                                    root_w + 2 * 4096, hA);
    // layer 3 (residual): hA -> hB
    aggregate_k<<<aggBlocks, 256, 0, stream>>>(hA, strt, deg, col, agg);
    dense_layer_k<1><<<dnsBlocks, 256, 0, stream>>>(agg, hA, rel_w + 3 * 4096, rel_b + 3 * 64,
                                                    root_w + 3 * 4096, hB);
    // layer 4 (residual): hB -> hA
    aggregate_k<<<aggBlocks, 256, 0, stream>>>(hB, strt, deg, col, agg);
    dense_layer_k<1><<<dnsBlocks, 256, 0, stream>>>(agg, hB, rel_w + 4 * 4096, rel_b + 4 * 64,
                                                    root_w + 4 * 4096, hA);

    // pool + head
    const int wavesPool = (NN + 31) / 32;
    pool_k<<<(wavesPool + 3) / 4, 256, 0, stream>>>(hA, batch, sums, cnt);
    head_k<<<(NG + 3) / 4, 256, 0, stream>>>(sums, cnt, lin_w, lin_b, out);
}